// Round 4
// baseline (243.931 us; speedup 1.0000x reference)
//
#include <hip/hip_runtime.h>
#include <hip/hip_bf16.h>
#include <math.h>

typedef short short8 __attribute__((ext_vector_type(8)));
typedef float f32x4 __attribute__((ext_vector_type(4)));

// ---- problem dims (fixed by setup_inputs) ----
#define BTN   128            // b*t
#define HWN   196            // 14*14
#define CCH   1024
#define NPIX  (BTN * HWN)    // 25088 = 98 * 256
#define BTSTR (CCH * HWN)    // 200704 floats per bt slab

// ---- workspace layout (bytes) ----
#define WS_D  0                      // d matrix bf16 [NPIX][1024]  = 51,380,224 B
#define WS_BW 51380224               // conv_w bf16 [1024][1024]    =  2,097,152 B

// ---- complex helpers ----
__device__ __forceinline__ float2 cadd(float2 a, float2 b) { return make_float2(a.x + b.x, a.y + b.y); }
__device__ __forceinline__ float2 csub(float2 a, float2 b) { return make_float2(a.x - b.x, a.y - b.y); }
__device__ __forceinline__ float2 cmulf(float2 a, float2 b) {
  return make_float2(a.x * b.x - a.y * b.y, a.x * b.y + a.y * b.x);
}
__device__ __forceinline__ float2 cmulc(float2 a, float2 b) {   // a * conj(b)
  return make_float2(a.x * b.x + a.y * b.y, a.y * b.x - a.x * b.y);
}
__device__ __forceinline__ float2 csqr(float2 a) {
  return make_float2(a.x * a.x - a.y * a.y, 2.f * a.x * a.y);
}
__device__ __forceinline__ float2 cneg(float2 a) { return make_float2(-a.x, -a.y); }
__device__ __forceinline__ unsigned short f2bf(float f) {   // RNE fp32->bf16
  unsigned u = __float_as_uint(f);
  unsigned r = (u + 0x7fffu + ((u >> 16) & 1u)) >> 16;
  return (unsigned short)r;
}

// ---------------------------------------------------------------- W -> bf16
__global__ void wcast_kernel(const float* __restrict__ w, unsigned short* __restrict__ o) {
  int i = (blockIdx.x * 256 + threadIdx.x) * 4;   // grid 1024 x 256 covers 1<<20
  float4 v = *(const float4*)(w + i);
  uint2 u;
  u.x = (unsigned)f2bf(v.x) | ((unsigned)f2bf(v.y) << 16);
  u.y = (unsigned)f2bf(v.z) | ((unsigned)f2bf(v.w) << 16);
  *(uint2*)(o + i) = u;
}

// ---------------------------------------------------------------- stage 1: FFT filter
// (unchanged from R3 — verified passing)
#define TS 1028

__global__ __launch_bounds__(256) void fft_filter_kernel(
    const float* __restrict__ x, const float* __restrict__ wfilt,
    unsigned short* __restrict__ dmat) {
  __shared__ float tile[8 * TS];
  __shared__ float2 tw10s[257];
  int tid = threadIdx.x;
  int l = tid & 63, w = tid >> 6;

  for (int i = tid; i < 257; i += 256) {
    float s, c;
    __sincosf(-6.283185307179586f * (float)i / 1024.0f, &s, &c);
    tw10s[i] = make_float2(c, s);
  }

  int blk = (blockIdx.x & 7) * 392 + (blockIdx.x >> 3);   // 3136 = 8 * 392
  int p_base = blk * 8;

  {
    int g = tid & 1, chb = tid >> 1;
    int p = p_base + 4 * g;
    int bt = p / HWN, hw = p - bt * HWN;          // hw%4==0, group stays in row
    const float* src = x + (size_t)bt * BTSTR + hw;
    float* rowb = tile + (4 * g) * TS;
#pragma unroll
    for (int it = 0; it < 8; ++it) {
      int c = chb + 128 * it;
      float4 v = *(const float4*)(src + (size_t)c * HWN);
      float* b = rowb + c;
      b[0 * TS] = v.x; b[1 * TS] = v.y; b[2 * TS] = v.z; b[3 * TS] = v.w;
    }
  }
  __syncthreads();

  const float H = 0.70710678118654752f;
  float2 Wl;
  { float s, c; __sincosf(-6.283185307179586f * (float)l / 512.0f, &s, &c); Wl = make_float2(c, s); }
  float2 W2l = csqr(Wl), W4l = csqr(W2l);
  float2 W2li = make_float2(W2l.y, -W2l.x);
  float2 T01 = cmulf(Wl, make_float2(H, -H));
  float2 T02 = make_float2(Wl.y, -Wl.x);
  float2 T03 = cmulf(Wl, make_float2(-H, -H));
  float2 t3 = csqr(W4l); if (l & 32) t3 = cneg(t3);
  float2 t4 = csqr(t3);  if (l & 16) t4 = cneg(t4);
  float2 t5 = csqr(t4);  if (l & 8)  t5 = cneg(t5);
  float2 t6 = csqr(t5);  if (l & 4)  t6 = cneg(t6);
  float2 t7 = csqr(t6);  if (l & 2)  t7 = cneg(t7);

#pragma unroll 1
  for (int pp = 0; pp < 2; ++pp) {
    int px = w * 2 + pp;
    int p = p_base + px;
    int bt = p / HWN, hw = p - bt * HWN;
    float2* zrow = (float2*)(tile + px * TS);

    float2 zr[8];
#pragma unroll
    for (int r = 0; r < 8; ++r) zr[r] = zrow[l + 64 * r];

    {
      float2 T0[4] = {Wl, T01, T02, T03};
#pragma unroll
      for (int r = 0; r < 4; ++r) {
        float2 a = zr[r], b = zr[r + 4];
        zr[r] = cadd(a, b);
        zr[r + 4] = cmulf(csub(a, b), T0[r]);
      }
    }
#pragma unroll
    for (int h = 0; h < 2; ++h) {
      int b0 = h * 4;
      float2 a = zr[b0], b = zr[b0 + 2];
      zr[b0] = cadd(a, b); zr[b0 + 2] = cmulf(csub(a, b), W2l);
      a = zr[b0 + 1]; b = zr[b0 + 3];
      zr[b0 + 1] = cadd(a, b); zr[b0 + 3] = cmulf(csub(a, b), W2li);
    }
#pragma unroll
    for (int r = 0; r < 8; r += 2) {
      float2 a = zr[r], b = zr[r + 1];
      zr[r] = cadd(a, b); zr[r + 1] = cmulf(csub(a, b), W4l);
    }
    {
      float2 tws[6] = {t3, t4, t5, t6, t7, make_float2(1.f, 0.f)};
      int masks[6] = {32, 16, 8, 4, 2, 1};
#pragma unroll
      for (int s = 0; s < 6; ++s) {
        int m = masks[s];
        bool up = (l & m) != 0;
        float2 te = up ? tws[s] : make_float2(1.f, 0.f);
#pragma unroll
        for (int r = 0; r < 8; ++r) {
          float2 v = zr[r];
          float2 o = make_float2(__shfl_xor(v.x, m, 64), __shfl_xor(v.y, m, 64));
          float2 d = up ? csub(o, v) : cadd(v, o);
          zr[r] = cmulf(d, te);
        }
      }
    }

#pragma unroll
    for (int r = 0; r < 8; ++r) zrow[l + 64 * r] = zr[r];
    {
      float2* z = zrow;
      const float* wf = wfilt + (size_t)((bt & 7) * HWN + hw) * 1026;
      const float sc = 1.0f / 512.0f;
#pragma unroll
      for (int i = 0; i < 4; ++i) {
        int f = 64 * i + l;
        if (f == 0) {
          float2 z0 = z[0];
          float X0 = z0.x + z0.y, X512 = z0.x - z0.y;
          float Y0 = X0 * wf[0] * sc;
          float Y512 = X512 * wf[1024] * sc;
          z[0] = make_float2(0.5f * (Y0 + Y512), 0.5f * (Y0 - Y512));
          float2 z2 = z[1];
          float2 X256 = make_float2(z2.x, -z2.y);
          float2 Y = cmulf(X256, make_float2(wf[512], wf[513]));
          z[1] = make_float2(Y.x * sc, -Y.y * sc);
        } else {
          int g = 512 - f;
          int pf = (int)(__brev((unsigned)f) >> 23);
          int pg = (int)(__brev((unsigned)g) >> 23);
          float2 Zf = z[pf], Zg = z[pg];
          float2 A = make_float2(0.5f * (Zf.x + Zg.x), 0.5f * (Zf.y - Zg.y));
          float2 B = make_float2(0.5f * (Zf.y + Zg.y), -0.5f * (Zf.x - Zg.x));
          float2 Wf = tw10s[f];
          float2 WB = cmulf(Wf, B);
          float2 Xf = make_float2(A.x + WB.x, A.y + WB.y);
          float2 Xg = make_float2(A.x - WB.x, -(A.y - WB.y));
          float2 Yf = cmulf(Xf, make_float2(wf[2 * f], wf[2 * f + 1]));
          float2 Yg = cmulf(Xg, make_float2(wf[2 * g], wf[2 * g + 1]));
          Yf.x *= sc; Yf.y *= sc; Yg.x *= sc; Yg.y *= sc;
          float2 Ap = make_float2(0.5f * (Yf.x + Yg.x), 0.5f * (Yf.y - Yg.y));
          float2 T  = make_float2(0.5f * (Yf.x - Yg.x), 0.5f * (Yf.y + Yg.y));
          float2 Bp = cmulf(make_float2(Wf.x, -Wf.y), T);
          z[pf] = make_float2(Ap.x - Bp.y, Ap.y + Bp.x);
          z[pg] = make_float2(Ap.x + Bp.y, Bp.x - Ap.y);
        }
      }
    }
#pragma unroll
    for (int r = 0; r < 8; ++r) zr[r] = zrow[l + 64 * r];

    {
      float2 tws[6] = {make_float2(1.f, 0.f), t7, t6, t5, t4, t3};
      int masks[6] = {1, 2, 4, 8, 16, 32};
#pragma unroll
      for (int s = 0; s < 6; ++s) {
        int m = masks[s];
        bool up = (l & m) != 0;
        float2 te = up ? make_float2(tws[s].x, -tws[s].y) : make_float2(1.f, 0.f);
#pragma unroll
        for (int r = 0; r < 8; ++r) {
          float2 v = cmulf(zr[r], te);
          float2 o = make_float2(__shfl_xor(v.x, m, 64), __shfl_xor(v.y, m, 64));
          zr[r] = up ? csub(o, v) : cadd(v, o);
        }
      }
    }
#pragma unroll
    for (int r = 0; r < 8; r += 2) {
      float2 v = cmulc(zr[r + 1], W4l);
      float2 a = zr[r];
      zr[r] = cadd(a, v); zr[r + 1] = csub(a, v);
    }
#pragma unroll
    for (int h = 0; h < 2; ++h) {
      int b0 = h * 4;
      float2 v = cmulc(zr[b0 + 2], W2l);
      float2 a = zr[b0];
      zr[b0] = cadd(a, v); zr[b0 + 2] = csub(a, v);
      v = cmulc(zr[b0 + 3], W2li);
      a = zr[b0 + 1];
      zr[b0 + 1] = cadd(a, v); zr[b0 + 3] = csub(a, v);
    }
    {
      float2 T0[4] = {Wl, T01, T02, T03};
#pragma unroll
      for (int r = 0; r < 4; ++r) {
        float2 v = cmulc(zr[r + 4], T0[r]);
        float2 a = zr[r];
        zr[r] = cadd(a, v); zr[r + 4] = csub(a, v);
      }
    }

    unsigned* dst = (unsigned*)(dmat + (size_t)p * CCH);
#pragma unroll
    for (int r = 0; r < 8; ++r) {
      float2 v = zr[r];
      dst[l + 64 * r] = (unsigned)f2bf(v.x) | ((unsigned)f2bf(v.y) << 16);
    }
  }
}

// ---------------------------------------------------------------- stage 2: GEMM + GELU + residual
// 256(px) x 256(ch) tile, BK=64, 16 K-tiles, 8 waves (2 ch-groups x 4 px-groups),
// 8-phase schedule: 4 quadrant-phases per K-tile, 1 half-tile staged per phase,
// one s_waitcnt vmcnt(4) per K-tile (loads fly across raw s_barriers).
// LDS 128KB dynamic: [buf][half] for W (channels) and D (pixels), 16KB halves.
// XOR swizzle (col16B ^= (row&7)<<4) applied via pre-swizzled global source +
// swizzled ds_read offsets (LDS written linearly by global_load_lds).
#define GLOAD16(gsrc, ldst)                                                     \
  __builtin_amdgcn_global_load_lds(                                             \
      (const __attribute__((address_space(1))) unsigned int*)(gsrc),            \
      (__attribute__((address_space(3))) unsigned int*)(ldst), 16, 0, 0)

extern __shared__ short S[];   // 65536 shorts = 128 KB

__device__ __forceinline__ void stage_gl(const unsigned short* __restrict__ gRow0,
                                         short* ldsHalf, int kcol, int w, int l) {
  // dest: wave-uniform base + lane*16B (linear). source: pre-swizzled per lane.
  int rb = w * 16 + (l >> 3);                       // row in half for load 0
  int cs = kcol + (((l & 7) ^ (l >> 3)) << 3);      // swizzled k col (shorts)
  GLOAD16(gRow0 + (size_t)rb * CCH + cs, ldsHalf + w * 1024);
  GLOAD16(gRow0 + (size_t)(rb + 8) * CCH + cs, ldsHalf + w * 1024 + 512);
}

__global__ __launch_bounds__(512, 2) void gemm_gelu_kernel(
    const unsigned short* __restrict__ A,   // d bf16 [NPIX][1024]
    const unsigned short* __restrict__ Bw,  // conv_w bf16 [o][c]
    const float* __restrict__ bias,
    const float* __restrict__ x,
    float* __restrict__ out) {
  // bijective XCD swizzle: 392 = 8 * 49
  int bid = blockIdx.x;
  int j = (bid & 7) * 49 + (bid >> 3);
  int mt = j >> 2, nt = j & 3;          // 98 pixel-tiles x 4 channel-tiles
  int p0 = mt * 256, n0 = nt * 256;

  int tid = threadIdx.x;
  int l = tid & 63, w = tid >> 6;       // wave id 0..7
  int wr = w >> 2, wc = w & 3;          // wr: channel group (2), wc: pixel group (4)
  int lr16 = l & 15, lg = l >> 4;

  // swizzled k-offsets for frag reads (shorts): (s*32+lg*8) ^ ((l&7)*8)
  int kx0 = (lg << 3) ^ ((l & 7) << 3);
  int kx1 = kx0 ^ 32;

  f32x4 acc[8][4];
#pragma unroll
  for (int m = 0; m < 8; ++m)
#pragma unroll
    for (int p = 0; p < 4; ++p) acc[m][p] = f32x4{0.f, 0.f, 0.f, 0.f};

  const unsigned short* Wg[2] = {Bw + (size_t)n0 * CCH, Bw + (size_t)(n0 + 128) * CCH};
  const unsigned short* Dg[2] = {A + (size_t)p0 * CCH, A + (size_t)(p0 + 128) * CCH};
  // LDS half bases (shorts): W: b*16384 + h*8192 ; D: 32768 + b*16384 + h*8192
#define LWB(b, h) (S + (b) * 16384 + (h) * 8192)
#define LDB(b, h) (S + 32768 + (b) * 16384 + (h) * 8192)
#define STG_W(b, h, kt) stage_gl(Wg[h], LWB(b, h), (kt) * 64, w, l)
#define STG_D(b, h, kt) stage_gl(Dg[h], LDB(b, h), (kt) * 64, w, l)

  // ---- prologue: tile0 (4 halves) + W0/D0 of tile1; keep last 2 in flight ----
  STG_W(0, 0, 0); STG_D(0, 0, 0); STG_W(0, 1, 0); STG_D(0, 1, 0);
  STG_W(1, 0, 1); STG_D(1, 0, 1);
  __builtin_amdgcn_sched_barrier(0);
  asm volatile("s_waitcnt vmcnt(4)" ::: "memory");
  __builtin_amdgcn_s_barrier();
  __builtin_amdgcn_sched_barrier(0);

  // ---- main loop: 16 K-tiles x 4 quadrant-phases ----
  // phase(MH,PH): read W-half MH, D-half PH frags; 16 MFMA; stage 1 half.
#define PHASE(MH, PH, STG, VM)                                                  \
  {                                                                             \
    short8 wf[4][2], df[2][2];                                                  \
    const short* wb = LWB(b, MH) + (wr * 64 + lr16) * 64;                       \
    const short* db = LDB(b, PH) + (wc * 32 + lr16) * 64;                       \
    _Pragma("unroll") for (int mr = 0; mr < 4; ++mr) {                          \
      wf[mr][0] = *(const short8*)(wb + mr * 1024 + kx0);                       \
      wf[mr][1] = *(const short8*)(wb + mr * 1024 + kx1);                       \
    }                                                                           \
    _Pragma("unroll") for (int pr = 0; pr < 2; ++pr) {                          \
      df[pr][0] = *(const short8*)(db + pr * 1024 + kx0);                       \
      df[pr][1] = *(const short8*)(db + pr * 1024 + kx1);                       \
    }                                                                           \
    STG;                                                                        \
    VM;                                                                         \
    __builtin_amdgcn_s_barrier();                                               \
    asm volatile("s_waitcnt lgkmcnt(0)" ::: "memory");                          \
    __builtin_amdgcn_sched_barrier(0);                                          \
    _Pragma("unroll") for (int mr = 0; mr < 4; ++mr)                            \
      _Pragma("unroll") for (int pr = 0; pr < 2; ++pr) {                        \
        acc[(MH)*4+mr][(PH)*2+pr] = __builtin_amdgcn_mfma_f32_16x16x32_bf16(    \
            wf[mr][0], df[pr][0], acc[(MH)*4+mr][(PH)*2+pr], 0, 0, 0);          \
        acc[(MH)*4+mr][(PH)*2+pr] = __builtin_amdgcn_mfma_f32_16x16x32_bf16(    \
            wf[mr][1], df[pr][1], acc[(MH)*4+mr][(PH)*2+pr], 0, 0, 0);          \
      }                                                                         \
    __builtin_amdgcn_s_barrier();                                               \
    __builtin_amdgcn_sched_barrier(0);                                          \
  }

#define VMG                                                                     \
  __builtin_amdgcn_sched_barrier(0);                                            \
  asm volatile("s_waitcnt vmcnt(4)" ::: "memory")

#pragma unroll 2
  for (int c = 0; c < 16; ++c) {
    const int b = c & 1;
    const int b1 = b ^ 1;
    const int c1 = (c + 1) & 15, c2 = (c + 2) & 15;   // wrapped tail prefetch
    PHASE(0, 0, STG_W(b1, 1, c1), );
    PHASE(0, 1, STG_D(b1, 1, c1), );
    PHASE(1, 0, STG_W(b, 0, c2), );
    PHASE(1, 1, STG_D(b, 0, c2), VMG);
  }
#undef PHASE
#undef VMG

  // ---- epilogue: bias + exact GELU + fp32 residual, coalesced along hw ----
#pragma unroll
  for (int m = 0; m < 8; ++m) {
    int ch = n0 + (m >> 2) * 128 + wr * 64 + (m & 3) * 16 + lg * 4;
#pragma unroll
    for (int p = 0; p < 4; ++p) {
      int px = p0 + (p >> 1) * 128 + wc * 32 + (p & 1) * 16 + lr16;
      int bt = px / HWN, hw = px - bt * HWN;
      size_t base = (size_t)bt * BTSTR + (size_t)ch * HWN + hw;
#pragma unroll
      for (int r = 0; r < 4; ++r) {
        size_t idx = base + (size_t)r * HWN;
        float v = acc[m][p][r] + bias[ch + r];
        float ge = 0.5f * v * (1.0f + erff(v * 0.70710678118654752f));
        out[idx] = x[idx] + ge;
      }
    }
  }
}

// ---------------------------------------------------------------- launcher
extern "C" void kernel_launch(void* const* d_in, const int* in_sizes, int n_in,
                              void* d_out, int out_size, void* d_ws, size_t ws_size,
                              hipStream_t stream) {
  const float* x      = (const float*)d_in[0];
  const float* wfilt  = (const float*)d_in[1];
  const float* conv_w = (const float*)d_in[2];
  const float* conv_b = (const float*)d_in[3];
  char* ws = (char*)d_ws;
  unsigned short* dmat = (unsigned short*)(ws + WS_D);
  unsigned short* bw   = (unsigned short*)(ws + WS_BW);
  float* out           = (float*)d_out;

  hipFuncSetAttribute((const void*)gemm_gelu_kernel,
                      hipFuncAttributeMaxDynamicSharedMemorySize, 131072);

  wcast_kernel<<<1024, 256, 0, stream>>>(conv_w, bw);
  fft_filter_kernel<<<3136, 256, 0, stream>>>(x, wfilt, dmat);
  gemm_gelu_kernel<<<392, 512, 131072, stream>>>(dmat, bw, conv_b, x, out);
}

// Round 5
// 214.180 us; speedup vs baseline: 1.1389x; 1.1389x over previous
//
#include <hip/hip_runtime.h>
#include <hip/hip_bf16.h>
#include <math.h>

typedef short short8 __attribute__((ext_vector_type(8)));
typedef float f32x4 __attribute__((ext_vector_type(4)));

// ---- problem dims (fixed by setup_inputs) ----
#define BTN   128            // b*t
#define HWN   196            // 14*14
#define CCH   1024
#define NPIX  (BTN * HWN)    // 25088
#define BTSTR (CCH * HWN)    // 200704 floats per bt slab

// ---- workspace layout (bytes) ----
#define WS_D  0                      // d matrix bf16 [NPIX][1024]
#define WS_BW 51380224               // conv_w bf16 [1024][1024]

// ---- complex helpers ----
__device__ __forceinline__ float2 cadd(float2 a, float2 b) { return make_float2(a.x + b.x, a.y + b.y); }
__device__ __forceinline__ float2 csub(float2 a, float2 b) { return make_float2(a.x - b.x, a.y - b.y); }
__device__ __forceinline__ float2 cmulf(float2 a, float2 b) {
  return make_float2(a.x * b.x - a.y * b.y, a.x * b.y + a.y * b.x);
}
__device__ __forceinline__ float2 cmulc(float2 a, float2 b) {   // a * conj(b)
  return make_float2(a.x * b.x + a.y * b.y, a.y * b.x - a.x * b.y);
}
__device__ __forceinline__ float2 csqr(float2 a) {
  return make_float2(a.x * a.x - a.y * a.y, 2.f * a.x * a.y);
}
__device__ __forceinline__ float2 cneg(float2 a) { return make_float2(-a.x, -a.y); }
__device__ __forceinline__ unsigned short f2bf(float f) {   // RNE fp32->bf16
  unsigned u = __float_as_uint(f);
  unsigned r = (u + 0x7fffu + ((u >> 16) & 1u)) >> 16;
  return (unsigned short)r;
}

// ---------------------------------------------------------------- W -> bf16
__global__ void wcast_kernel(const float* __restrict__ w, unsigned short* __restrict__ o) {
  int i = (blockIdx.x * 256 + threadIdx.x) * 4;
  float4 v = *(const float4*)(w + i);
  uint2 u;
  u.x = (unsigned)f2bf(v.x) | ((unsigned)f2bf(v.y) << 16);
  u.y = (unsigned)f2bf(v.z) | ((unsigned)f2bf(v.w) << 16);
  *(uint2*)(o + i) = u;
}

// ---------------------------------------------------------------- stage 1: FFT filter
// (unchanged from R3 — verified passing)
#define TS 1028

__global__ __launch_bounds__(256) void fft_filter_kernel(
    const float* __restrict__ x, const float* __restrict__ wfilt,
    unsigned short* __restrict__ dmat) {
  __shared__ float tile[8 * TS];
  __shared__ float2 tw10s[257];
  int tid = threadIdx.x;
  int l = tid & 63, w = tid >> 6;

  for (int i = tid; i < 257; i += 256) {
    float s, c;
    __sincosf(-6.283185307179586f * (float)i / 1024.0f, &s, &c);
    tw10s[i] = make_float2(c, s);
  }

  int blk = (blockIdx.x & 7) * 392 + (blockIdx.x >> 3);
  int p_base = blk * 8;

  {
    int g = tid & 1, chb = tid >> 1;
    int p = p_base + 4 * g;
    int bt = p / HWN, hw = p - bt * HWN;
    const float* src = x + (size_t)bt * BTSTR + hw;
    float* rowb = tile + (4 * g) * TS;
#pragma unroll
    for (int it = 0; it < 8; ++it) {
      int c = chb + 128 * it;
      float4 v = *(const float4*)(src + (size_t)c * HWN);
      float* b = rowb + c;
      b[0 * TS] = v.x; b[1 * TS] = v.y; b[2 * TS] = v.z; b[3 * TS] = v.w;
    }
  }
  __syncthreads();

  const float H = 0.70710678118654752f;
  float2 Wl;
  { float s, c; __sincosf(-6.283185307179586f * (float)l / 512.0f, &s, &c); Wl = make_float2(c, s); }
  float2 W2l = csqr(Wl), W4l = csqr(W2l);
  float2 W2li = make_float2(W2l.y, -W2l.x);
  float2 T01 = cmulf(Wl, make_float2(H, -H));
  float2 T02 = make_float2(Wl.y, -Wl.x);
  float2 T03 = cmulf(Wl, make_float2(-H, -H));
  float2 t3 = csqr(W4l); if (l & 32) t3 = cneg(t3);
  float2 t4 = csqr(t3);  if (l & 16) t4 = cneg(t4);
  float2 t5 = csqr(t4);  if (l & 8)  t5 = cneg(t5);
  float2 t6 = csqr(t5);  if (l & 4)  t6 = cneg(t6);
  float2 t7 = csqr(t6);  if (l & 2)  t7 = cneg(t7);

#pragma unroll 1
  for (int pp = 0; pp < 2; ++pp) {
    int px = w * 2 + pp;
    int p = p_base + px;
    int bt = p / HWN, hw = p - bt * HWN;
    float2* zrow = (float2*)(tile + px * TS);

    float2 zr[8];
#pragma unroll
    for (int r = 0; r < 8; ++r) zr[r] = zrow[l + 64 * r];

    {
      float2 T0[4] = {Wl, T01, T02, T03};
#pragma unroll
      for (int r = 0; r < 4; ++r) {
        float2 a = zr[r], b = zr[r + 4];
        zr[r] = cadd(a, b);
        zr[r + 4] = cmulf(csub(a, b), T0[r]);
      }
    }
#pragma unroll
    for (int h = 0; h < 2; ++h) {
      int b0 = h * 4;
      float2 a = zr[b0], b = zr[b0 + 2];
      zr[b0] = cadd(a, b); zr[b0 + 2] = cmulf(csub(a, b), W2l);
      a = zr[b0 + 1]; b = zr[b0 + 3];
      zr[b0 + 1] = cadd(a, b); zr[b0 + 3] = cmulf(csub(a, b), W2li);
    }
#pragma unroll
    for (int r = 0; r < 8; r += 2) {
      float2 a = zr[r], b = zr[r + 1];
      zr[r] = cadd(a, b); zr[r + 1] = cmulf(csub(a, b), W4l);
    }
    {
      float2 tws[6] = {t3, t4, t5, t6, t7, make_float2(1.f, 0.f)};
      int masks[6] = {32, 16, 8, 4, 2, 1};
#pragma unroll
      for (int s = 0; s < 6; ++s) {
        int m = masks[s];
        bool up = (l & m) != 0;
        float2 te = up ? tws[s] : make_float2(1.f, 0.f);
#pragma unroll
        for (int r = 0; r < 8; ++r) {
          float2 v = zr[r];
          float2 o = make_float2(__shfl_xor(v.x, m, 64), __shfl_xor(v.y, m, 64));
          float2 d = up ? csub(o, v) : cadd(v, o);
          zr[r] = cmulf(d, te);
        }
      }
    }

#pragma unroll
    for (int r = 0; r < 8; ++r) zrow[l + 64 * r] = zr[r];
    {
      float2* z = zrow;
      const float* wf = wfilt + (size_t)((bt & 7) * HWN + hw) * 1026;
      const float sc = 1.0f / 512.0f;
#pragma unroll
      for (int i = 0; i < 4; ++i) {
        int f = 64 * i + l;
        if (f == 0) {
          float2 z0 = z[0];
          float X0 = z0.x + z0.y, X512 = z0.x - z0.y;
          float Y0 = X0 * wf[0] * sc;
          float Y512 = X512 * wf[1024] * sc;
          z[0] = make_float2(0.5f * (Y0 + Y512), 0.5f * (Y0 - Y512));
          float2 z2 = z[1];
          float2 X256 = make_float2(z2.x, -z2.y);
          float2 Y = cmulf(X256, make_float2(wf[512], wf[513]));
          z[1] = make_float2(Y.x * sc, -Y.y * sc);
        } else {
          int g = 512 - f;
          int pf = (int)(__brev((unsigned)f) >> 23);
          int pg = (int)(__brev((unsigned)g) >> 23);
          float2 Zf = z[pf], Zg = z[pg];
          float2 A = make_float2(0.5f * (Zf.x + Zg.x), 0.5f * (Zf.y - Zg.y));
          float2 B = make_float2(0.5f * (Zf.y + Zg.y), -0.5f * (Zf.x - Zg.x));
          float2 Wf = tw10s[f];
          float2 WB = cmulf(Wf, B);
          float2 Xf = make_float2(A.x + WB.x, A.y + WB.y);
          float2 Xg = make_float2(A.x - WB.x, -(A.y - WB.y));
          float2 Yf = cmulf(Xf, make_float2(wf[2 * f], wf[2 * f + 1]));
          float2 Yg = cmulf(Xg, make_float2(wf[2 * g], wf[2 * g + 1]));
          Yf.x *= sc; Yf.y *= sc; Yg.x *= sc; Yg.y *= sc;
          float2 Ap = make_float2(0.5f * (Yf.x + Yg.x), 0.5f * (Yf.y - Yg.y));
          float2 T  = make_float2(0.5f * (Yf.x - Yg.x), 0.5f * (Yf.y + Yg.y));
          float2 Bp = cmulf(make_float2(Wf.x, -Wf.y), T);
          z[pf] = make_float2(Ap.x - Bp.y, Ap.y + Bp.x);
          z[pg] = make_float2(Ap.x + Bp.y, Bp.x - Ap.y);
        }
      }
    }
#pragma unroll
    for (int r = 0; r < 8; ++r) zr[r] = zrow[l + 64 * r];

    {
      float2 tws[6] = {make_float2(1.f, 0.f), t7, t6, t5, t4, t3};
      int masks[6] = {1, 2, 4, 8, 16, 32};
#pragma unroll
      for (int s = 0; s < 6; ++s) {
        int m = masks[s];
        bool up = (l & m) != 0;
        float2 te = up ? make_float2(tws[s].x, -tws[s].y) : make_float2(1.f, 0.f);
#pragma unroll
        for (int r = 0; r < 8; ++r) {
          float2 v = cmulf(zr[r], te);
          float2 o = make_float2(__shfl_xor(v.x, m, 64), __shfl_xor(v.y, m, 64));
          zr[r] = up ? csub(o, v) : cadd(v, o);
        }
      }
    }
#pragma unroll
    for (int r = 0; r < 8; r += 2) {
      float2 v = cmulc(zr[r + 1], W4l);
      float2 a = zr[r];
      zr[r] = cadd(a, v); zr[r + 1] = csub(a, v);
    }
#pragma unroll
    for (int h = 0; h < 2; ++h) {
      int b0 = h * 4;
      float2 v = cmulc(zr[b0 + 2], W2l);
      float2 a = zr[b0];
      zr[b0] = cadd(a, v); zr[b0 + 2] = csub(a, v);
      v = cmulc(zr[b0 + 3], W2li);
      a = zr[b0 + 1];
      zr[b0 + 1] = cadd(a, v); zr[b0 + 3] = csub(a, v);
    }
    {
      float2 T0[4] = {Wl, T01, T02, T03};
#pragma unroll
      for (int r = 0; r < 4; ++r) {
        float2 v = cmulc(zr[r + 4], T0[r]);
        float2 a = zr[r];
        zr[r] = cadd(a, v); zr[r + 4] = csub(a, v);
      }
    }

    unsigned* dst = (unsigned*)(dmat + (size_t)p * CCH);
#pragma unroll
    for (int r = 0; r < 8; ++r) {
      float2 v = zr[r];
      dst[l + 64 * r] = (unsigned)f2bf(v.x) | ((unsigned)f2bf(v.y) << 16);
    }
  }
}

// ---------------------------------------------------------------- stage 2: GEMM + GELU + residual
// R3 skeleton (128px x 256ch tile, BK=32, 8 waves 2x4, dbuf 48KB, 2 blocks/CU)
// + counted vmcnt(3) with raw s_barrier (loads stay in flight across barriers)
// + 2-way LDS swizzle: source chunk ^= (row>>1)&3, matching ds_read XOR
// + s_setprio around MFMA cluster + sched_barrier fences.
#define GLOAD16(gsrc, ldst)                                                     \
  __builtin_amdgcn_global_load_lds(                                             \
      (const __attribute__((address_space(1))) unsigned int*)(gsrc),            \
      (__attribute__((address_space(3))) unsigned int*)(ldst), 16, 0, 0)

__global__ __launch_bounds__(512) void gemm_gelu_kernel(
    const unsigned short* __restrict__ A,   // d bf16 [NPIX][1024]
    const unsigned short* __restrict__ Bw,  // conv_w bf16 [o][c]
    const float* __restrict__ bias,
    const float* __restrict__ x,
    float* __restrict__ out) {
  __shared__ unsigned short lA[2 * 128 * 32];   // 16 KB (pixels)
  __shared__ unsigned short lB[2 * 256 * 32];   // 32 KB (channels)

  // XCD swizzle: 784 = 8 XCD * 98; n-inner so 4 n-tiles sharing an A-panel
  // run consecutively on the same XCD.
  int bid = blockIdx.x;
  int X = bid & 7, slot = bid >> 3;
  int j = X * 98 + slot;
  int mt = j >> 2, nt = j & 3;
  int p0 = mt * 128, n0 = nt * 256;

  int tid = threadIdx.x;
  int l = tid & 63, wid = tid >> 6;
  int wr = wid >> 2, wc = wid & 3;   // wave tile: pixels p0+wr*64, channels n0+wc*64
  int lr = l & 15, lg = l >> 4;

  f32x4 acc[4][4];   // [channel frag][pixel frag]
#pragma unroll
  for (int i = 0; i < 4; ++i)
#pragma unroll
    for (int jj = 0; jj < 4; ++jj) acc[i][jj] = f32x4{0.f, 0.f, 0.f, 0.f};

  // staging: thread -> (row = tid>>2, chunk) with chunk source-swizzled:
  // LDS slot (row, c) holds global chunk c ^ ((row>>1)&3).
  int arow = tid >> 2;
  int acg = (tid & 3) ^ ((tid >> 3) & 3);
  const unsigned short* ag  = A  + (size_t)(p0 + arow) * CCH + acg * 8;
  const unsigned short* bg0 = Bw + (size_t)(n0 + arow) * CCH + acg * 8;
  const unsigned short* bg1 = bg0 + (size_t)128 * CCH;
  unsigned short* laW = lA + wid * 512;   // wave-uniform LDS bases (lane*16B HW-added)
  unsigned short* lbW = lB + wid * 512;

  // frag-read k-offset (shorts): logical chunk lg lives at lg ^ ((row>>1)&3);
  // row = (64|16)*k + lr so (row>>1)&3 == (lr>>1)&3 for all frags.
  int kx = ((lg ^ ((lr >> 1) & 3)) << 3);
  const unsigned short* lAf0 = lA + (wr * 64 + lr) * 32 + kx;
  const unsigned short* lBf0 = lB + (wc * 64 + lr) * 32 + kx;

#define STAGE(buf, kk)                                                          \
  do {                                                                          \
    GLOAD16(ag  + (kk) * 32, laW + (buf) * 4096);                               \
    GLOAD16(bg0 + (kk) * 32, lbW + (buf) * 8192);                               \
    GLOAD16(bg1 + (kk) * 32, lbW + (buf) * 8192 + 4096);                        \
  } while (0)

  STAGE(0, 0);
  __builtin_amdgcn_sched_barrier(0);
  asm volatile("s_waitcnt vmcnt(0)" ::: "memory");
  __builtin_amdgcn_s_barrier();
  __builtin_amdgcn_sched_barrier(0);

  int cur = 0;
#pragma unroll 2
  for (int kk = 0; kk < 32; ++kk) {
    // prefetch next tile into the other buffer (dead since last iter's barrier)
    STAGE(cur ^ 1, (kk + 1) & 31);                 // wrap: last iter re-stages t0 (dead)
    __builtin_amdgcn_sched_barrier(0);
    asm volatile("s_waitcnt vmcnt(3)" ::: "memory");   // wait ONLY current tile's 3
    __builtin_amdgcn_s_barrier();                      // all waves' cur loads landed
    __builtin_amdgcn_sched_barrier(0);

    short8 af[4], bf[4];
    const unsigned short* lAf = lAf0 + cur * 4096;
    const unsigned short* lBf = lBf0 + cur * 8192;
#pragma unroll
    for (int m = 0; m < 4; ++m) af[m] = *(const short8*)(lAf + m * 512);
#pragma unroll
    for (int n = 0; n < 4; ++n) bf[n] = *(const short8*)(lBf + n * 512);
    __builtin_amdgcn_s_setprio(1);
#pragma unroll
    for (int i = 0; i < 4; ++i)       // channel frags (W rows as M)
#pragma unroll
      for (int jj = 0; jj < 4; ++jj)  // pixel frags (d rows as N)
        acc[i][jj] = __builtin_amdgcn_mfma_f32_16x16x32_bf16(bf[i], af[jj], acc[i][jj], 0, 0, 0);
    __builtin_amdgcn_s_setprio(0);
    __builtin_amdgcn_sched_barrier(0);
    __builtin_amdgcn_s_barrier();                      // reads done -> cur re-stageable
    __builtin_amdgcn_sched_barrier(0);
    cur ^= 1;
  }
#undef STAGE
  asm volatile("s_waitcnt vmcnt(0)" ::: "memory");     // drain wrap-stage leftovers

  // epilogue: D row = (lane>>4)*4 + reg (=channel), col = lane&15 (=pixel)
  // jj innermost: 4 adjacent 64B stores -> 256B merged windows.
  int pxb[4], btb[4], hwb[4];
#pragma unroll
  for (int jj = 0; jj < 4; ++jj) {
    pxb[jj] = p0 + wr * 64 + jj * 16 + lr;
    btb[jj] = pxb[jj] / HWN;
    hwb[jj] = pxb[jj] - btb[jj] * HWN;
  }
#pragma unroll
  for (int i = 0; i < 4; ++i) {
    int ch = n0 + wc * 64 + i * 16 + lg * 4;
#pragma unroll
    for (int r = 0; r < 4; ++r) {
      float bcol = bias[ch + r];
#pragma unroll
      for (int jj = 0; jj < 4; ++jj) {
        size_t idx = (size_t)btb[jj] * BTSTR + (size_t)(ch + r) * HWN + hwb[jj];
        float v = acc[i][jj][r] + bcol;
        float ge = 0.5f * v * (1.0f + erff(v * 0.70710678118654752f));
        out[idx] = x[idx] + ge;
      }
    }
  }
}

// ---------------------------------------------------------------- launcher
extern "C" void kernel_launch(void* const* d_in, const int* in_sizes, int n_in,
                              void* d_out, int out_size, void* d_ws, size_t ws_size,
                              hipStream_t stream) {
  const float* x      = (const float*)d_in[0];
  const float* wfilt  = (const float*)d_in[1];
  const float* conv_w = (const float*)d_in[2];
  const float* conv_b = (const float*)d_in[3];
  char* ws = (char*)d_ws;
  unsigned short* dmat = (unsigned short*)(ws + WS_D);
  unsigned short* bw   = (unsigned short*)(ws + WS_BW);
  float* out           = (float*)d_out;

  wcast_kernel<<<1024, 256, 0, stream>>>(conv_w, bw);
  fft_filter_kernel<<<3136, 256, 0, stream>>>(x, wfilt, dmat);
  gemm_gelu_kernel<<<784, 512, 0, stream>>>(dmat, bw, conv_b, x, out);
}